// Round 1
// baseline (404.830 us; speedup 1.0000x reference)
//
#include <hip/hip_runtime.h>
#include <hip/hip_bf16.h>
#include <cstdint>
#include <cstddef>

// Problem dims (fixed by setup_inputs)
#define B_N   64
#define T_N   500
#define K_IN  1250
#define N_H   512
#define N_OUT 2
#define M_N   (B_N * T_N)   // 32000

// GEMM1 tiling
#define BM 128
#define BN 128
#define BK 32

static_assert(M_N % BM == 0, "M tiling");
static_assert(N_H % BN == 0, "N tiling");

typedef __attribute__((ext_vector_type(8))) short bf16x8;  // 8 bf16 = 4 VGPRs
typedef __attribute__((ext_vector_type(4))) float f32x4;   // MFMA acc

#define DECAY_SR  0.9048374180359595732f   // exp(-1/10)
#define DECAY_REF 0.3678794411714423216f   // exp(-1)
#define THETA 10.0f

__device__ __forceinline__ short f2bf(float f) {
  // round-to-nearest-even fp32 -> bf16
  union { float f; uint32_t u; } v; v.f = f;
  uint32_t r = v.u + 0x7FFFu + ((v.u >> 16) & 1u);
  return (short)(r >> 16);
}
__device__ __forceinline__ float bf2f(short s) {
  union { uint32_t u; float f; } v;
  v.u = ((uint32_t)(uint16_t)s) << 16;
  return v.f;
}

// ---------------------------------------------------------------------------
// GEMM1: U1[m][n] = sum_k X[m][k] * W1[n][k]   (m=32000, n=512, k=1250)
// bf16 MFMA 16x16x32. Block = 4 waves (2x2), wave tile 64x64 (4x4 frags).
// fp32->bf16 conversion happens during LDS staging (no pre-pass).
// k-pairing: k = (lane>>4)*8 + elem, identical for A and B (layout-agnostic).
// ---------------------------------------------------------------------------
__global__ __launch_bounds__(256) void gemm1_kernel(const float* __restrict__ X,
                                                    const float* __restrict__ W1,
                                                    float* __restrict__ U1) {
  __shared__ short As[BM][BK];   // [m][k] bf16, rows 64B -> bank-distributed
  __shared__ short Bs[BN][BK];   // [n][k] bf16
  const int tid  = threadIdx.x;
  const int bm   = blockIdx.x * BM;
  const int bn   = blockIdx.y * BN;
  const int w    = tid >> 6;
  const int lane = tid & 63;
  const int wr   = w >> 1;        // 0..1
  const int wc   = w & 1;         // 0..1
  const int lrow = lane & 15;
  const int lgrp = lane >> 4;

  f32x4 acc[4][4];
  #pragma unroll
  for (int i = 0; i < 4; ++i)
    #pragma unroll
    for (int j = 0; j < 4; ++j)
      acc[i][j] = (f32x4){0.f, 0.f, 0.f, 0.f};

  for (int k0 = 0; k0 < K_IN; k0 += BK) {
    // ---- stage A (x) and B (W1) tiles, converting fp32 -> bf16 ----
    #pragma unroll
    for (int rr = 0; rr < 4; ++rr) {
      int j   = rr * 256 + tid;        // 0..1023
      int row = j >> 3;                // 0..127
      int kq  = (j & 7) * 4;           // 0,4,...,28
      int gk  = k0 + kq;
      const float* srcA = X  + (size_t)(bm + row) * K_IN + gk;
      const float* srcB = W1 + (size_t)(bn + row) * K_IN + gk;
      float a0, a1, a2, a3, b0, b1, b2, b3;
      if (gk + 3 < K_IN) {
        // rows are 8B-aligned here (1250 even, kq multiple of 4)
        float2 x0 = *(const float2*)srcA;
        float2 x1 = *(const float2*)(srcA + 2);
        float2 y0 = *(const float2*)srcB;
        float2 y1 = *(const float2*)(srcB + 2);
        a0 = x0.x; a1 = x0.y; a2 = x1.x; a3 = x1.y;
        b0 = y0.x; b1 = y0.y; b2 = y1.x; b3 = y1.y;
      } else {  // k tail (1250 = 39*32 + 2): zero-pad
        a0 = (gk + 0 < K_IN) ? srcA[0] : 0.f;
        a1 = (gk + 1 < K_IN) ? srcA[1] : 0.f;
        a2 = (gk + 2 < K_IN) ? srcA[2] : 0.f;
        a3 = (gk + 3 < K_IN) ? srcA[3] : 0.f;
        b0 = (gk + 0 < K_IN) ? srcB[0] : 0.f;
        b1 = (gk + 1 < K_IN) ? srcB[1] : 0.f;
        b2 = (gk + 2 < K_IN) ? srcB[2] : 0.f;
        b3 = (gk + 3 < K_IN) ? srcB[3] : 0.f;
      }
      short4 ha; ha.x = f2bf(a0); ha.y = f2bf(a1); ha.z = f2bf(a2); ha.w = f2bf(a3);
      short4 hb; hb.x = f2bf(b0); hb.y = f2bf(b1); hb.z = f2bf(b2); hb.w = f2bf(b3);
      *(short4*)&As[row][kq] = ha;
      *(short4*)&Bs[row][kq] = hb;
    }
    __syncthreads();

    // ---- fragments + MFMA ----
    bf16x8 af[4], bfv[4];
    #pragma unroll
    for (int i = 0; i < 4; ++i) {
      af[i]  = *(const bf16x8*)&As[wr * 64 + i * 16 + lrow][lgrp * 8];
      bfv[i] = *(const bf16x8*)&Bs[wc * 64 + i * 16 + lrow][lgrp * 8];
    }
    #pragma unroll
    for (int i = 0; i < 4; ++i)
      #pragma unroll
      for (int j = 0; j < 4; ++j)
        acc[i][j] = __builtin_amdgcn_mfma_f32_16x16x32_bf16(af[i], bfv[j], acc[i][j], 0, 0, 0);
    __syncthreads();
  }

  // ---- epilogue: C/D mapping col=lane&15, row=(lane>>4)*4+reg ----
  #pragma unroll
  for (int i = 0; i < 4; ++i) {
    int rowb = bm + wr * 64 + i * 16 + lgrp * 4;
    #pragma unroll
    for (int j = 0; j < 4; ++j) {
      int col = bn + wc * 64 + j * 16 + lrow;
      #pragma unroll
      for (int r = 0; r < 4; ++r)
        U1[(size_t)(rowb + r) * N_H + col] = acc[i][j][r];
    }
  }
}

// ---------------------------------------------------------------------------
// Scan1: per (b,h) chain over T: p = d*p + u; v = p + r; s = (v>=theta);
//        r = dref*(r - 20*s). Writes s1 as bf16 (exact 0/1).
// 10-deep load batches to keep HBM latency hidden at low occupancy.
// ---------------------------------------------------------------------------
__global__ __launch_bounds__(256) void scan1_kernel(const float* __restrict__ U1,
                                                    short* __restrict__ S1) {
  int idx = blockIdx.x * 256 + threadIdx.x;  // 0..32767 = b*512 + h
  int b = idx >> 9, h = idx & 511;
  const float* u = U1 + (size_t)b * T_N * N_H + h;
  short*       s = S1 + (size_t)b * T_N * N_H + h;
  float p = 0.f, r = 0.f;
  for (int t0 = 0; t0 < T_N; t0 += 10) {
    float buf[10];
    #pragma unroll
    for (int j = 0; j < 10; ++j) buf[j] = u[(size_t)(t0 + j) * N_H];
    #pragma unroll
    for (int j = 0; j < 10; ++j) {
      p = DECAY_SR * p + buf[j];
      float v = p + r;
      float sp = (v >= THETA) ? 1.f : 0.f;
      r = DECAY_REF * (r - 2.f * THETA * sp);
      s[(size_t)(t0 + j) * N_H] = (sp > 0.f) ? (short)0x3F80 : (short)0;
    }
  }
}

// ---------------------------------------------------------------------------
// GEMM2: U2[m][o] = sum_h S1[m][h] * W2[o][h]  (o=0..1). One wave per m-row.
// ---------------------------------------------------------------------------
__global__ __launch_bounds__(256) void gemm2_kernel(const short* __restrict__ S1,
                                                    const float* __restrict__ W2,
                                                    float* __restrict__ U2) {
  int m    = blockIdx.x * 4 + (threadIdx.x >> 6);
  int lane = threadIdx.x & 63;
  const bf16x8 sv = *(const bf16x8*)&S1[(size_t)m * N_H + lane * 8];
  float a0 = 0.f, a1 = 0.f;
  #pragma unroll
  for (int j = 0; j < 8; ++j) {
    float sj = bf2f(sv[j]);
    a0 += sj * W2[lane * 8 + j];
    a1 += sj * W2[N_H + lane * 8 + j];
  }
  #pragma unroll
  for (int off = 32; off >= 1; off >>= 1) {
    a0 += __shfl_down(a0, off);
    a1 += __shfl_down(a1, off);
  }
  if (lane == 0) {
    U2[(size_t)m * 2]     = a0;
    U2[(size_t)m * 2 + 1] = a1;
  }
}

// ---------------------------------------------------------------------------
// Scan2: per-b block; stage u2[b] (500x2) in LDS, lanes 0/1 run the scans.
// ---------------------------------------------------------------------------
__global__ __launch_bounds__(128) void scan2_kernel(const float* __restrict__ U2,
                                                    float* __restrict__ OUT) {
  __shared__ float lu[T_N * 2];
  __shared__ float ls[T_N * 2];
  int b = blockIdx.x;
  const float* src = U2 + (size_t)b * T_N * 2;
  for (int i = threadIdx.x; i < T_N * 2; i += 128) lu[i] = src[i];
  __syncthreads();
  if (threadIdx.x < 2) {
    int o = threadIdx.x;
    float p = 0.f, r = 0.f;
    for (int t = 0; t < T_N; ++t) {
      p = DECAY_SR * p + lu[t * 2 + o];
      float v = p + r;
      float sp = (v >= THETA) ? 1.f : 0.f;
      r = DECAY_REF * (r - 2.f * THETA * sp);
      ls[t * 2 + o] = sp;
    }
  }
  __syncthreads();
  float* dst = OUT + (size_t)b * T_N * 2;
  for (int i = threadIdx.x; i < T_N * 2; i += 128) dst[i] = ls[i];
}

// ---------------------------------------------------------------------------
extern "C" void kernel_launch(void* const* d_in, const int* in_sizes, int n_in,
                              void* d_out, int out_size, void* d_ws, size_t ws_size,
                              hipStream_t stream) {
  const float* X  = (const float*)d_in[0];   // (64,500,1250)
  const float* W1 = (const float*)d_in[1];   // (512,1250)
  const float* W2 = (const float*)d_in[2];   // (2,512)
  float* OUT = (float*)d_out;                // (64,500,2)

  char* ws = (char*)d_ws;
  float* U1 = (float*)ws;                                      // 65,536,000 B
  short* S1 = (short*)(ws + (size_t)M_N * N_H * 4);            // 32,768,000 B
  float* U2 = (float*)(ws + (size_t)M_N * N_H * 6);            //    256,000 B

  gemm1_kernel<<<dim3(M_N / BM, N_H / BN), 256, 0, stream>>>(X, W1, U1);
  scan1_kernel<<<dim3((B_N * N_H) / 256), 256, 0, stream>>>(U1, S1);
  gemm2_kernel<<<dim3(M_N / 4), 256, 0, stream>>>(S1, W2, U2);
  scan2_kernel<<<dim3(B_N), 128, 0, stream>>>(U2, OUT);
}

// Round 2
// 357.256 us; speedup vs baseline: 1.1332x; 1.1332x over previous
//
#include <hip/hip_runtime.h>
#include <hip/hip_bf16.h>
#include <cstdint>
#include <cstddef>

// Problem dims
#define B_N   64
#define T_N   500
#define K_IN  1250
#define KP    1280          // K padded to multiple of 32 (zero-filled)
#define N_H   512
#define M_N   (B_N * T_N)   // 32000

// GEMM1 tiling: BM x full-N (512), 16 waves (4x4), wave tile 32x128
#define BM 128
#define BK 32

typedef __attribute__((ext_vector_type(8))) short bf16x8;  // 8 bf16 = 4 VGPRs
typedef __attribute__((ext_vector_type(4))) float f32x4;   // MFMA acc

#define DECAY_SR  0.9048374180359595732f   // exp(-1/10)
#define DECAY_REF 0.3678794411714423216f   // exp(-1)
#define THETA 10.0f

__device__ __forceinline__ short f2bf(float f) {
  // round-to-nearest-even fp32 -> bf16
  union { float f; uint32_t u; } v; v.f = f;
  uint32_t r = v.u + 0x7FFFu + ((v.u >> 16) & 1u);
  return (short)(r >> 16);
}
__device__ __forceinline__ float bf2f(unsigned short s) {
  union { uint32_t u; float f; } v;
  v.u = ((uint32_t)s) << 16;
  return v.f;
}

// ---------------------------------------------------------------------------
// Pre-pass: W1 (512x1250 fp32) -> W1b (512x1280 bf16, zero-padded tail).
// ---------------------------------------------------------------------------
__global__ __launch_bounds__(256) void w1cvt_kernel(const float* __restrict__ W1,
                                                    short* __restrict__ W1b) {
  int k = blockIdx.x * 256 + threadIdx.x;   // 0..1279
  int n = blockIdx.y;                        // 0..511
  float v = (k < K_IN) ? W1[(size_t)n * K_IN + k] : 0.f;
  W1b[(size_t)n * KP + k] = f2bf(v);
}

// ---------------------------------------------------------------------------
// GEMM1: U1[m][n] = sum_k X[m][k] * W1[n][k]  (m=32000, n=512, k=1250)
// Block: 128 x 512 tile, 1024 threads (16 waves, 4x4), BK=32.
// B staged via global_load_lds (16B) from pre-converted bf16 W1b with
// pre-swizzled SOURCE addresses (linear LDS dest) + swizzled ds_read.
// A staged fp32->bf16 inline (1 float2-pair per thread) with swizzled write.
// Swizzle: 16B slot' = slot ^ (row & 3)  (involution, both-sides).
// k-pairing for fragments: k = (lane>>4)*8 + elem, identical A and B.
// ---------------------------------------------------------------------------
__global__ __launch_bounds__(1024) void gemm1_kernel(const float* __restrict__ X,
                                                     const short* __restrict__ W1b,
                                                     unsigned short* __restrict__ U1) {
  __shared__ short As[BM * BK];    // 8 KiB,  [row][slot'][8]
  __shared__ short Bs[N_H * BK];   // 32 KiB, [n][slot'][8]
  const int tid  = threadIdx.x;
  const int bm   = blockIdx.x * BM;
  const int w    = tid >> 6;       // 0..15
  const int lane = tid & 63;
  const int wr   = w >> 2;         // 0..3  (row group of 32)
  const int wc   = w & 3;          // 0..3  (col group of 128)
  const int lrow = lane & 15;
  const int lgrp = lane >> 4;
  const int lsw  = lgrp ^ (lrow & 3);   // swizzled slot for fragment reads

  f32x4 acc[2][8];
  #pragma unroll
  for (int i = 0; i < 2; ++i)
    #pragma unroll
    for (int j = 0; j < 8; ++j)
      acc[i][j] = (f32x4){0.f, 0.f, 0.f, 0.f};

  // A staging map: 1024 threads cover 128x32 (4 elts = 1x float2-pair each)
  const int arow  = tid >> 3;          // 0..127
  const int akq   = (tid & 7) * 4;     // 0,4,...,28 (shorts/fp32 elems)
  const int aslot = akq >> 3;          // 0..3
  const int asub  = akq & 7;           // 0 or 4 shorts within 16B slot
  const int awofs = arow * BK + ((aslot ^ (arow & 3)) * 8) + asub;

  // B staging map: 32 chunks of 1KiB; wave w does chunks w*2, w*2+1.
  // LDS linear: chunk*1024B + lane*16B  ->  n = chunk*16 + (lane>>2), slot' = lane&3
  // source slot = slot' ^ (n&3)
  const int bn0   = w * 32 + (lane >> 2);          // n for c=0
  const int bslot = lane & 3;

  for (int k0 = 0; k0 < KP; k0 += BK) {
    // ---- B: direct global->LDS DMA, pre-swizzled source ----
    #pragma unroll
    for (int c = 0; c < 2; ++c) {
      int n = bn0 + c * 16;
      int sslot = bslot ^ (n & 3);
      const short* src = W1b + (size_t)n * KP + k0 + sslot * 8;
      short* dst = &Bs[(w * 2 + c) * 512];
      __builtin_amdgcn_global_load_lds(
          (const __attribute__((address_space(1))) void*)src,
          (__attribute__((address_space(3))) void*)dst, 16, 0, 0);
    }
    // ---- A: fp32 load + cvt + swizzled ds_write ----
    {
      int gk = k0 + akq;
      const float* srcA = X + (size_t)(bm + arow) * K_IN + gk;
      float a0, a1, a2, a3;
      if (gk + 3 < K_IN) {
        float2 x0 = *(const float2*)srcA;
        float2 x1 = *(const float2*)(srcA + 2);
        a0 = x0.x; a1 = x0.y; a2 = x1.x; a3 = x1.y;
      } else {  // tail K-step (k0=1248): zero-pad
        a0 = (gk + 0 < K_IN) ? srcA[0] : 0.f;
        a1 = (gk + 1 < K_IN) ? srcA[1] : 0.f;
        a2 = (gk + 2 < K_IN) ? srcA[2] : 0.f;
        a3 = (gk + 3 < K_IN) ? srcA[3] : 0.f;
      }
      short4 h;
      h.x = f2bf(a0); h.y = f2bf(a1); h.z = f2bf(a2); h.w = f2bf(a3);
      *(short4*)&As[awofs] = h;
    }
    __syncthreads();

    // ---- fragments + MFMA ----
    bf16x8 af[2], bfv[8];
    #pragma unroll
    for (int i = 0; i < 2; ++i)
      af[i] = *(const bf16x8*)&As[(wr * 32 + i * 16 + lrow) * BK + lsw * 8];
    #pragma unroll
    for (int j = 0; j < 8; ++j)
      bfv[j] = *(const bf16x8*)&Bs[(wc * 128 + j * 16 + lrow) * BK + lsw * 8];
    #pragma unroll
    for (int i = 0; i < 2; ++i)
      #pragma unroll
      for (int j = 0; j < 8; ++j)
        acc[i][j] = __builtin_amdgcn_mfma_f32_16x16x32_bf16(af[i], bfv[j], acc[i][j], 0, 0, 0);
    __syncthreads();
  }

  // ---- epilogue: C/D map col=lane&15, row=(lane>>4)*4+reg; U1 bf16 ----
  #pragma unroll
  for (int i = 0; i < 2; ++i) {
    int row0 = bm + wr * 32 + i * 16 + lgrp * 4;
    #pragma unroll
    for (int j = 0; j < 8; ++j) {
      int col = wc * 128 + j * 16 + lrow;
      #pragma unroll
      for (int r = 0; r < 4; ++r)
        U1[(size_t)(row0 + r) * N_H + col] = (unsigned short)f2bf(acc[i][j][r]);
    }
  }
}

// ---------------------------------------------------------------------------
// Scan1: per (b,h) chain over T (bf16 input). 10-deep load batches.
// ---------------------------------------------------------------------------
__global__ __launch_bounds__(256) void scan1_kernel(const unsigned short* __restrict__ U1,
                                                    short* __restrict__ S1) {
  int idx = blockIdx.x * 256 + threadIdx.x;  // b*512 + h
  int b = idx >> 9, h = idx & 511;
  const unsigned short* u = U1 + (size_t)b * T_N * N_H + h;
  short*                s = S1 + (size_t)b * T_N * N_H + h;
  float p = 0.f, r = 0.f;
  for (int t0 = 0; t0 < T_N; t0 += 10) {
    unsigned short raw[10];
    #pragma unroll
    for (int j = 0; j < 10; ++j) raw[j] = u[(size_t)(t0 + j) * N_H];
    #pragma unroll
    for (int j = 0; j < 10; ++j) {
      p = DECAY_SR * p + bf2f(raw[j]);
      float v = p + r;
      float sp = (v >= THETA) ? 1.f : 0.f;
      r = DECAY_REF * (r - 2.f * THETA * sp);
      s[(size_t)(t0 + j) * N_H] = (sp > 0.f) ? (short)0x3F80 : (short)0;
    }
  }
}

// ---------------------------------------------------------------------------
// GEMM2: U2[m][o] = sum_h S1[m][h] * W2[o][h]  (o=0..1). One wave per m-row.
// ---------------------------------------------------------------------------
__global__ __launch_bounds__(256) void gemm2_kernel(const short* __restrict__ S1,
                                                    const float* __restrict__ W2,
                                                    float* __restrict__ U2) {
  int m    = blockIdx.x * 4 + (threadIdx.x >> 6);
  int lane = threadIdx.x & 63;
  const bf16x8 sv = *(const bf16x8*)&S1[(size_t)m * N_H + lane * 8];
  float a0 = 0.f, a1 = 0.f;
  #pragma unroll
  for (int j = 0; j < 8; ++j) {
    float sj = bf2f((unsigned short)sv[j]);
    a0 += sj * W2[lane * 8 + j];
    a1 += sj * W2[N_H + lane * 8 + j];
  }
  #pragma unroll
  for (int off = 32; off >= 1; off >>= 1) {
    a0 += __shfl_down(a0, off);
    a1 += __shfl_down(a1, off);
  }
  if (lane == 0) {
    U2[(size_t)m * 2]     = a0;
    U2[(size_t)m * 2 + 1] = a1;
  }
}

// ---------------------------------------------------------------------------
// Scan2: per-b block; stage u2[b] (500x2) in LDS, lanes 0/1 run the scans.
// ---------------------------------------------------------------------------
__global__ __launch_bounds__(128) void scan2_kernel(const float* __restrict__ U2,
                                                    float* __restrict__ OUT) {
  __shared__ float lu[T_N * 2];
  __shared__ float ls[T_N * 2];
  int b = blockIdx.x;
  const float* src = U2 + (size_t)b * T_N * 2;
  for (int i = threadIdx.x; i < T_N * 2; i += 128) lu[i] = src[i];
  __syncthreads();
  if (threadIdx.x < 2) {
    int o = threadIdx.x;
    float p = 0.f, r = 0.f;
    for (int t = 0; t < T_N; ++t) {
      p = DECAY_SR * p + lu[t * 2 + o];
      float v = p + r;
      float sp = (v >= THETA) ? 1.f : 0.f;
      r = DECAY_REF * (r - 2.f * THETA * sp);
      ls[t * 2 + o] = sp;
    }
  }
  __syncthreads();
  float* dst = OUT + (size_t)b * T_N * 2;
  for (int i = threadIdx.x; i < T_N * 2; i += 128) dst[i] = ls[i];
}

// ---------------------------------------------------------------------------
extern "C" void kernel_launch(void* const* d_in, const int* in_sizes, int n_in,
                              void* d_out, int out_size, void* d_ws, size_t ws_size,
                              hipStream_t stream) {
  const float* X  = (const float*)d_in[0];   // (64,500,1250)
  const float* W1 = (const float*)d_in[1];   // (512,1250)
  const float* W2 = (const float*)d_in[2];   // (2,512)
  float* OUT = (float*)d_out;                // (64,500,2)

  char* ws = (char*)d_ws;
  short*          W1b = (short*)ws;                               // 1,310,720 B
  unsigned short* U1  = (unsigned short*)(ws + 1310720);          // 32,768,000 B
  short*          S1  = (short*)(ws + 1310720 + 32768000);        // 32,768,000 B
  float*          U2  = (float*)(ws + 1310720 + 2 * 32768000);    //    256,000 B

  w1cvt_kernel<<<dim3(KP / 256, N_H), 256, 0, stream>>>(W1, W1b);
  gemm1_kernel<<<dim3(M_N / BM), 1024, 0, stream>>>(X, W1b, U1);
  scan1_kernel<<<dim3((B_N * N_H) / 256), 256, 0, stream>>>(U1, S1);
  gemm2_kernel<<<dim3(M_N / 4), 256, 0, stream>>>(S1, W2, U2);
  scan2_kernel<<<dim3(B_N), 128, 0, stream>>>(U2, OUT);
}